// Round 20
// baseline (101.835 us; speedup 1.0000x reference)
//
#include <hip/hip_runtime.h>
#include <hip/hip_bf16.h>

typedef __attribute__((ext_vector_type(8))) short bf16x8;
typedef __attribute__((ext_vector_type(4))) float f32x4;

#define DEVI __device__ __forceinline__

// exp2 everywhere: Q pre-scaled by (1/sqrt(32))*log2(e) in the qkv-GEMM epilogue.
#define QSCALE 0.2550348744f        /* (1/sqrt(32)) * log2(e) */
#if __has_builtin(__builtin_amdgcn_exp2f)
DEVI float exp2x(float x) { return __builtin_amdgcn_exp2f(x); }
#else
DEVI float exp2x(float x) { float r; asm("v_exp_f32 %0, %1" : "=v"(r) : "v"(x)); return r; }
#endif

DEVI unsigned short f2bf(float f) {
  __hip_bfloat16 h = __float2bfloat16(f);
  return *reinterpret_cast<unsigned short*>(&h);
}

DEVI float bf2f(unsigned short u) {
  union { unsigned u; float f; } v; v.u = ((unsigned)u) << 16; return v.f;
}

DEVI unsigned cvtpk(float lo, float hi) {
  unsigned r;
  asm("v_cvt_pk_bf16_f32 %0, %1, %2" : "=v"(r) : "v"(lo), "v"(hi));
  return r;
}

DEVI void gload16(const void* g, void* l) {
  __builtin_amdgcn_global_load_lds((const __attribute__((address_space(1))) void*)g,
                                   (__attribute__((address_space(3))) void*)l, 16, 0, 0);
}

// ---------------- fused: LN1+transpose (blocks 0..511) | weight casts (blocks 512..1279) ----------------
__global__ __launch_bounds__(256) void k_pre(const float* __restrict__ x,
                                             const float* __restrict__ g,
                                             const float* __restrict__ be,
                                             unsigned short* __restrict__ xt,
                                             unsigned short* __restrict__ xln,
                                             const float* __restrict__ wa, const float* __restrict__ wb,
                                             const float* __restrict__ wc, const float* __restrict__ wd,
                                             unsigned short* __restrict__ oa, unsigned short* __restrict__ ob,
                                             unsigned short* __restrict__ oc, unsigned short* __restrict__ od) {
  __shared__ float tile[256][33];
  const int t = threadIdx.x;
  if (blockIdx.x >= 512) {
    const int i4 = ((blockIdx.x - 512) * 256 + t) * 4;
    const float* src; unsigned short* dst; int off;
    if (i4 < 196608)      { src = wa; dst = oa; off = 0; }
    else if (i4 < 262144) { src = wb; dst = ob; off = 196608; }
    else if (i4 < 524288) { src = wc; dst = oc; off = 262144; }
    else                  { src = wd; dst = od; off = 524288; }
    const int j = i4 - off;
    const float4 v = *(const float4*)(src + j);
    ushort4 o;
    o.x = f2bf(v.x); o.y = f2bf(v.y); o.z = f2bf(v.z); o.w = f2bf(v.w);
    *(ushort4*)(dst + j) = o;
    return;
  }
  const int b  = blockIdx.x >> 5;
  const int p0 = (blockIdx.x & 31) * 32;
  const float* src = x + ((size_t)b * 256 + t) * 1024 + p0;
#pragma unroll
  for (int j = 0; j < 32; j += 4) {
    float4 v = *(const float4*)(src + j);
    tile[t][j] = v.x; tile[t][j + 1] = v.y; tile[t][j + 2] = v.z; tile[t][j + 3] = v.w;
  }
  __syncthreads();
  const int w = t >> 6, l = t & 63;
#pragma unroll
  for (int i = 0; i < 8; i++) {
    const int p = w * 8 + i;
    float s = 0.f, ss = 0.f;
#pragma unroll
    for (int q = 0; q < 4; q++) {
      float v = tile[l + 64 * q][p];
      s += v; ss += v * v;
    }
#pragma unroll
    for (int msk = 1; msk < 64; msk <<= 1) {
      s  += __shfl_xor(s, msk);
      ss += __shfl_xor(ss, msk);
    }
    const float mean = s * (1.f / 256.f);
    const float var  = ss * (1.f / 256.f) - mean * mean;
    const float rs   = rsqrtf(var + 1e-5f);
    const size_t token = (size_t)b * 1024 + p0 + p;
#pragma unroll
    for (int q = 0; q < 4; q++) {
      const int c = l + 64 * q;
      const float v = tile[c][p];
      xt[token * 256 + c]  = f2bf(v);
      xln[token * 256 + c] = f2bf((v - mean) * rs * g[c] + be[c]);
    }
  }
}

// ---------------- 8-wave GEMM (512 thr): BM=128 x BN=128, dbuf, T2-swizzled ----------------
// Wave grid 4m x 2n (wave tile 32x64). C[M,N] = A[M,K] @ B[N,K]^T.
// EPI 0: bf16 out (qkv); Q cols (n0<256) pre-scaled by QSCALE; n0>=512 (V): swapped MFMA -> vT
// EPI 2: +bias, relu -> bf16 (ffn1)
// EPI 3: swapped MFMA; +bias +bf16 addend(y) -> out[b][c][s] fp32 (folds transpose)
template <int EPI, int NN>
__global__ __launch_bounds__(512) void k_gemm8w(const unsigned short* __restrict__ A, int lda,
                                                const unsigned short* __restrict__ Bw, int ldb,
                                                int K,
                                                const float* __restrict__ bias,
                                                const unsigned short* __restrict__ addend,
                                                float* __restrict__ outf,
                                                unsigned short* __restrict__ outb, int ldc,
                                                unsigned short* __restrict__ vtb) {
  __shared__ __align__(16) unsigned short As[2][128 * 64];
  __shared__ __align__(16) unsigned short Bs[2][128 * 64];
  const int nwg = gridDim.x;
  const int id  = (blockIdx.x & 7) * (nwg >> 3) + (blockIdx.x >> 3);
  const int m0  = (id / NN) * 128, n0 = (id % NN) * 128;
  const int t  = threadIdx.x;
  const int w  = t >> 6, l = t & 63;
  const int wm = (w >> 1) * 32, wn = (w & 1) * 64;
  const int lr = l & 15, hi = l >> 4;
  const bool swp = (EPI == 3) || ((EPI == 0) && (n0 >= 512));
  const float qs = ((EPI == 0) && (n0 < 256)) ? QSCALE : 1.f;
  f32x4 acc[2][4] = {};
  const int nkt = K >> 6;
  const int e   = t * 8;
  const int er  = e >> 6;                        // t>>3 : 0..63
  const int ecs = (((t & 7) ^ (er & 7)) * 8);    // pre-swizzled source column
  const int sxr = lr & 7;

#pragma unroll
  for (int i = 0; i < 2; i++) {
    gload16(&A[(size_t)(m0 + er + i * 64) * lda + ecs], &As[0][e + i * 4096]);
    gload16(&Bw[(size_t)(n0 + er + i * 64) * ldb + ecs], &Bs[0][e + i * 4096]);
  }

  for (int kt = 0; kt < nkt; ++kt) {
    const int cur = kt & 1;
    __syncthreads();
    if (kt + 1 < nkt) {
      const int kn = (kt + 1) * 64;
#pragma unroll
      for (int i = 0; i < 2; i++) {
        gload16(&A[(size_t)(m0 + er + i * 64) * lda + kn + ecs], &As[cur ^ 1][e + i * 4096]);
        gload16(&Bw[(size_t)(n0 + er + i * 64) * ldb + kn + ecs], &Bs[cur ^ 1][e + i * 4096]);
      }
    }
#pragma unroll
    for (int ks = 0; ks < 2; ks++) {
      const int sA = ((ks * 4 + hi) ^ sxr) * 8;
      bf16x8 af[2], bfr[4];
#pragma unroll
      for (int i = 0; i < 2; i++) af[i] = *(const bf16x8*)&As[cur][(wm + i * 16 + lr) * 64 + sA];
#pragma unroll
      for (int j = 0; j < 4; j++) bfr[j] = *(const bf16x8*)&Bs[cur][(wn + j * 16 + lr) * 64 + sA];
      if (swp) {
#pragma unroll
        for (int i = 0; i < 2; i++)
#pragma unroll
          for (int j = 0; j < 4; j++)
            acc[i][j] = __builtin_amdgcn_mfma_f32_16x16x32_bf16(bfr[j], af[i], acc[i][j], 0, 0, 0);
      } else {
#pragma unroll
        for (int i = 0; i < 2; i++)
#pragma unroll
          for (int j = 0; j < 4; j++)
            acc[i][j] = __builtin_amdgcn_mfma_f32_16x16x32_bf16(af[i], bfr[j], acc[i][j], 0, 0, 0);
      }
    }
  }

  if constexpr (EPI == 3) {
#pragma unroll
    for (int i = 0; i < 2; i++)
#pragma unroll
      for (int j = 0; j < 4; j++)
#pragma unroll
        for (int r = 0; r < 4; r++) {
          const int c  = n0 + wn + j * 16 + hi * 4 + r;
          const int gm = m0 + wm + i * 16 + lr;
          const int b  = gm >> 10, sI = gm & 1023;
          outf[((size_t)b * 256 + c) * 1024 + sI] =
              acc[i][j][r] + bias[c] + bf2f(addend[(size_t)gm * 256 + c]);
        }
    return;
  }
  if ((EPI == 0) && (n0 >= 512)) {
#pragma unroll
    for (int i = 0; i < 2; i++)
#pragma unroll
      for (int j = 0; j < 4; j++)
#pragma unroll
        for (int r = 0; r < 4; r++) {
          const int gn = n0 + wn + j * 16 + hi * 4 + r;
          const int gm = m0 + wm + i * 16 + lr;
          const int c = gn - 512;
          const int b = gm >> 10;
          vtb[(size_t)(b * 256 + c) * 1024 + (gm & 1023)] = f2bf(acc[i][j][r]);
        }
    return;
  }
#pragma unroll
  for (int i = 0; i < 2; i++)
#pragma unroll
    for (int j = 0; j < 4; j++)
#pragma unroll
      for (int r = 0; r < 4; r++) {
        const int gr = m0 + wm + i * 16 + hi * 4 + r;
        const int gc = n0 + wn + j * 16 + lr;
        const float v = acc[i][j][r];
        if constexpr (EPI == 0) {
          outb[(size_t)gr * ldc + gc] = f2bf(v * qs);
        } else if constexpr (EPI == 2) {
          const float z = v + bias[gc];
          outb[(size_t)gr * ldc + gc] = f2bf(z > 0.f ? z : 0.f);
        }
      }
}

// ---------------- proj-GEMM + residual + LN2 fused (BM=32, BN=256), T2-swizzled ----------------
__global__ __launch_bounds__(256) void k_gemm1ln(const unsigned short* __restrict__ A,
                                                 const unsigned short* __restrict__ Bw,
                                                 const float* __restrict__ bias,
                                                 const unsigned short* __restrict__ xt,
                                                 const float* __restrict__ g2,
                                                 const float* __restrict__ be2,
                                                 unsigned short* __restrict__ y,
                                                 unsigned short* __restrict__ yln) {
  __shared__ __align__(16) unsigned short As[2][32 * 64];
  __shared__ __align__(16) unsigned short Bs[2][256 * 64];
  __shared__ float red[32][4][2];
  __shared__ float2 stats[32];
  const int id = (blockIdx.x & 7) * 64 + (blockIdx.x >> 3);  // bijective (512 % 8 == 0)
  const int m0 = id * 32;
  const int t  = threadIdx.x;
  const int w  = t >> 6, l = t & 63;
  const int wn = w * 64;
  const int lr = l & 15, hi = l >> 4;
  f32x4 acc[2][4] = {};
  const int e   = t * 8;
  const int er  = e >> 6;
  const int ecs = (((t & 7) ^ (er & 7)) * 8);
  const int sxr = lr & 7;

  gload16(&A[(size_t)(m0 + er) * 256 + ecs], &As[0][e]);
#pragma unroll
  for (int i = 0; i < 8; i++)
    gload16(&Bw[(size_t)(er + i * 32) * 256 + ecs], &Bs[0][e + i * 2048]);

  for (int kt = 0; kt < 4; ++kt) {
    const int cur = kt & 1;
    __syncthreads();
    if (kt < 3) {
      const int kn = (kt + 1) * 64;
      gload16(&A[(size_t)(m0 + er) * 256 + kn + ecs], &As[cur ^ 1][e]);
#pragma unroll
      for (int i = 0; i < 8; i++)
        gload16(&Bw[(size_t)(er + i * 32) * 256 + kn + ecs], &Bs[cur ^ 1][e + i * 2048]);
    }
#pragma unroll
    for (int ks = 0; ks < 2; ks++) {
      const int sA = ((ks * 4 + hi) ^ sxr) * 8;
      bf16x8 af[2], bfr[4];
#pragma unroll
      for (int i = 0; i < 2; i++) af[i] = *(const bf16x8*)&As[cur][(i * 16 + lr) * 64 + sA];
#pragma unroll
      for (int j = 0; j < 4; j++) bfr[j] = *(const bf16x8*)&Bs[cur][(wn + j * 16 + lr) * 64 + sA];
#pragma unroll
      for (int i = 0; i < 2; i++)
#pragma unroll
        for (int j = 0; j < 4; j++)
          acc[i][j] = __builtin_amdgcn_mfma_f32_16x16x32_bf16(af[i], bfr[j], acc[i][j], 0, 0, 0);
    }
  }

#pragma unroll
  for (int i = 0; i < 2; i++)
#pragma unroll
    for (int j = 0; j < 4; j++)
#pragma unroll
      for (int r = 0; r < 4; r++) {
        const int gr = i * 16 + hi * 4 + r;
        const int gc = wn + j * 16 + lr;
        acc[i][j][r] += bias[gc] + bf2f(xt[(size_t)(m0 + gr) * 256 + gc]);
      }

#pragma unroll
  for (int i = 0; i < 2; i++)
#pragma unroll
    for (int r = 0; r < 4; r++) {
      float s = 0.f, ss = 0.f;
#pragma unroll
      for (int j = 0; j < 4; j++) {
        const float v = acc[i][j][r];
        s += v; ss += v * v;
      }
#pragma unroll
      for (int msk = 1; msk < 16; msk <<= 1) {
        s  += __shfl_xor(s, msk);
        ss += __shfl_xor(ss, msk);
      }
      if (lr == 0) {
        red[i * 16 + hi * 4 + r][w][0] = s;
        red[i * 16 + hi * 4 + r][w][1] = ss;
      }
    }
  __syncthreads();
  if (t < 32) {
    const float s  = red[t][0][0] + red[t][1][0] + red[t][2][0] + red[t][3][0];
    const float ss = red[t][0][1] + red[t][1][1] + red[t][2][1] + red[t][3][1];
    const float mean = s * (1.f / 256.f);
    const float var  = ss * (1.f / 256.f) - mean * mean;
    stats[t] = make_float2(mean, rsqrtf(var + 1e-5f));
  }
  __syncthreads();

#pragma unroll
  for (int i = 0; i < 2; i++)
#pragma unroll
    for (int r = 0; r < 4; r++) {
      const int gr = i * 16 + hi * 4 + r;
      const float2 st = stats[gr];
      const size_t rowoff = (size_t)(m0 + gr) * 256;
#pragma unroll
      for (int j = 0; j < 4; j++) {
        const int gc = wn + j * 16 + lr;
        const float v = acc[i][j][r];
        y[rowoff + gc]   = f2bf(v);
        yln[rowoff + gc] = f2bf((v - st.x) * st.y * g2[gc] + be2[gc]);
      }
    }
}

// ---------------- flash attention: 512 thr / 8 waves, qi=4 (512 q-rows/block), dbuf LDS ----------------
__global__ __launch_bounds__(512, 1) void k_attn(const unsigned short* __restrict__ qkv,
                                                 const unsigned short* __restrict__ vt,
                                                 unsigned short* __restrict__ attn_out) {
  __shared__ __align__(16) unsigned short Ks[2][2][64][40];
  __shared__ __align__(16) unsigned short Vs[2][2][32][72];

  const int bid  = blockIdx.x;
  const int wgid = (bid & 7) * 32 + (bid >> 3);  // bijective (256 % 8 == 0)
  const int bh = wgid >> 1;
  const int qt = wgid & 1;
  const int b = bh >> 3, h = bh & 7;
  const int q0 = qt * 512;
  const int t = threadIdx.x, w = t >> 6, l = t & 63;
  const int lr = l & 15, hi = l >> 4, lk = hi * 8;
  const size_t base  = (size_t)b * 1024 * 512;
  const size_t vbase = (size_t)bh * 32 * 1024;

  bf16x8 qf[4];
#pragma unroll
  for (int qi = 0; qi < 4; qi++)
    qf[qi] = *(const bf16x8*)&qkv[base + (size_t)(q0 + w * 64 + qi * 16 + lr) * 512 + h * 32 + lk];

  f32x4 o0[4] = {}, o1[4] = {}, o_s[4] = {};
  const f32x4 z4 = {0.f, 0.f, 0.f, 0.f};
  const bf16x8 ones = {16256, 16256, 16256, 16256, 16256, 16256, 16256, 16256};  // bf16 1.0

  const int stok = t >> 2;             // 0..127
  const int sd0  = (t & 3) * 8;
  const int ksub = stok >> 6;
  const int krow = stok & 63;
  const int prow = ((krow >> 2) & 1) * 16 + ((krow >> 3) & 3) * 4 + (krow & 3) + (krow & 32);
  const int vsd  = t >> 4;             // 0..31
  const int vtk  = (t & 15) * 8;       // 0..120
  const int vsub = vtk >> 6;
  const int voff = vtk & 63;

  const unsigned short* pk = &qkv[base + (size_t)stok * 512 + 256 + h * 32 + sd0];
  const unsigned short* pv = &vt[vbase + (size_t)vsd * 1024 + vtk];
  bf16x8 nk = *(const bf16x8*)pk;
  bf16x8 nv = *(const bf16x8*)pv;

  for (int it = 0; it < 8; ++it) {
    const int cur = it & 1;
    *(bf16x8*)&Ks[cur][ksub][prow][sd0] = nk;
    *(bf16x8*)&Vs[cur][vsub][vsd][voff] = nv;
    __syncthreads();

    if (it < 7) {
      pk += 128 * 512;
      pv += 128;
      nk = *(const bf16x8*)pk;
      nv = *(const bf16x8*)pv;
    }

#pragma unroll
    for (int sub = 0; sub < 2; ++sub) {
      bf16x8 kf[4];
#pragma unroll
      for (int blk = 0; blk < 4; blk++)
        kf[blk] = *(const bf16x8*)&Ks[cur][sub][blk * 16 + lr][lk];

      union U { unsigned u[4]; bf16x8 v; };
      U pa[4][2];
#pragma unroll
      for (int qi = 0; qi < 4; qi++) {
        f32x4 s[4];
        __builtin_amdgcn_s_setprio(1);
#pragma unroll
        for (int blk = 0; blk < 4; blk++)
          s[blk] = __builtin_amdgcn_mfma_f32_16x16x32_bf16(kf[blk], qf[qi], z4, 0, 0, 0);
        __builtin_amdgcn_s_setprio(0);
#pragma unroll
        for (int blk = 0; blk < 4; blk++) {
          const float p0 = exp2x(s[blk][0]);
          const float p1 = exp2x(s[blk][1]);
          const float p2 = exp2x(s[blk][2]);
          const float p3 = exp2x(s[blk][3]);
          pa[qi][blk >> 1].u[(blk & 1) * 2]     = cvtpk(p0, p1);
          pa[qi][blk >> 1].u[(blk & 1) * 2 + 1] = cvtpk(p2, p3);
        }
      }

      __builtin_amdgcn_s_setprio(1);
#pragma unroll
      for (int ks = 0; ks < 2; ks++) {
        const bf16x8 v0f = *(const bf16x8*)&Vs[cur][sub][lr][ks * 32 + lk];
        const bf16x8 v1f = *(const bf16x8*)&Vs[cur][sub][16 + lr][ks * 32 + lk];
#pragma unroll
        for (int qi = 0; qi < 4; qi++) {
          o0[qi]  = __builtin_amdgcn_mfma_f32_16x16x32_bf16(pa[qi][ks].v, v0f, o0[qi], 0, 0, 0);
          o1[qi]  = __builtin_amdgcn_mfma_f32_16x16x32_bf16(pa[qi][ks].v, v1f, o1[qi], 0, 0, 0);
          o_s[qi] = __builtin_amdgcn_mfma_f32_16x16x32_bf16(pa[qi][ks].v, ones, o_s[qi], 0, 0, 0);
        }
      }
      __builtin_amdgcn_s_setprio(0);
    }
  }

#pragma unroll
  for (int qi = 0; qi < 4; qi++)
#pragma unroll
    for (int r = 0; r < 4; r++) {
      const float inv = __builtin_amdgcn_rcpf(o_s[qi][r]);
      const int row = q0 + w * 64 + qi * 16 + hi * 4 + r;
      attn_out[(size_t)(b * 1024 + row) * 256 + h * 32 + lr]      = f2bf(o0[qi][r] * inv);
      attn_out[(size_t)(b * 1024 + row) * 256 + h * 32 + 16 + lr] = f2bf(o1[qi][r] * inv);
    }
}

// ---------------- launch ----------------
extern "C" void kernel_launch(void* const* d_in, const int* in_sizes, int n_in,
                              void* d_out, int out_size, void* d_ws, size_t ws_size,
                              hipStream_t stream) {
  const float* x      = (const float*)d_in[0];
  const float* w_qkv  = (const float*)d_in[1];
  const float* w_proj = (const float*)d_in[2];
  const float* b_proj = (const float*)d_in[3];
  const float* g1     = (const float*)d_in[4];
  const float* beta1  = (const float*)d_in[5];
  const float* g2     = (const float*)d_in[6];
  const float* beta2  = (const float*)d_in[7];
  const float* w1     = (const float*)d_in[8];
  const float* b1     = (const float*)d_in[9];
  const float* w2     = (const float*)d_in[10];
  const float* b2     = (const float*)d_in[11];
  float* out = (float*)d_out;
  char* ws = (char*)d_ws;

  constexpr size_t OFF_XT  = 0;                       //  8 MB bf16 [tok][256]
  constexpr size_t OFF_XLN = 16777216;                //  8 MB bf16
  constexpr size_t OFF_QKV = OFF_XLN + 8388608;       // 16 MB bf16 [tok][512] (Q,K only)
  constexpr size_t OFF_ATT = OFF_QKV + 16777216;      //  8 MB bf16
  constexpr size_t OFF_Y   = OFF_ATT + 8388608;       //  8 MB bf16 (aliases vT before gemm1ln)
  constexpr size_t OFF_YLN = OFF_Y + 16777216;        //  8 MB bf16
  constexpr size_t OFF_W   = OFF_YLN + 8388608;       // weights bf16
  constexpr size_t OFF_H1  = OFF_XLN;                 // alias: 32 MB bf16 [tok][1024]
  constexpr size_t OFF_VT  = OFF_Y;                   // alias: 8 MB bf16 [bh][32][1024]

  unsigned short* xt    = (unsigned short*)(ws + OFF_XT);
  unsigned short* xln   = (unsigned short*)(ws + OFF_XLN);
  unsigned short* qkv   = (unsigned short*)(ws + OFF_QKV);
  unsigned short* attn  = (unsigned short*)(ws + OFF_ATT);
  unsigned short* y     = (unsigned short*)(ws + OFF_Y);
  unsigned short* yln   = (unsigned short*)(ws + OFF_YLN);
  unsigned short* h1    = (unsigned short*)(ws + OFF_H1);
  unsigned short* vtb   = (unsigned short*)(ws + OFF_VT);
  unsigned short* wqkvb = (unsigned short*)(ws + OFF_W);
  unsigned short* wprjb = (unsigned short*)(ws + OFF_W + 393216);
  unsigned short* w1b   = (unsigned short*)(ws + OFF_W + 393216 + 131072);
  unsigned short* w2b   = (unsigned short*)(ws + OFF_W + 393216 + 131072 + 524288);

  // LN1+transpose (512 blocks) || weight casts (768 blocks)
  k_pre<<<1280, 256, 0, stream>>>(x, g1, beta1, xt, xln,
                                  w_qkv, w_proj, w1, w2, wqkvb, wprjb, w1b, w2b);

  // qkv = xln @ w_qkv^T : Q (log2-prescaled),K -> qkv[tok][512]; V -> vT[bh][d][tok]
  k_gemm8w<0, 6><<<768, 512, 0, stream>>>(xln, 256, wqkvb, 256, 256,
                                          nullptr, nullptr, nullptr, qkv, 512, vtb);

  k_attn<<<256, 512, 0, stream>>>(qkv, vtb, attn);

  // y = attn @ w_proj^T + b_proj + xt ; yln = LN2(y)  (fused)
  k_gemm1ln<<<512, 256, 0, stream>>>(attn, wprjb, b_proj, xt, g2, beta2, y, yln);

  // h1 = relu(yln @ w1^T + b1)
  k_gemm8w<2, 8><<<1024, 512, 0, stream>>>(yln, 256, w1b, 256, 256,
                                           b1, nullptr, nullptr, h1, 1024, nullptr);

  // out = transpose(h1 @ w2^T + b2 + y)  (direct [b][c][s] write)
  k_gemm8w<3, 2><<<256, 512, 0, stream>>>(h1, 1024, w2b, 1024, 1024,
                                          b2, y, out, nullptr, 0, nullptr);
}

// Round 21
// 100.718 us; speedup vs baseline: 1.0111x; 1.0111x over previous
//
#include <hip/hip_runtime.h>
#include <hip/hip_bf16.h>

typedef __attribute__((ext_vector_type(8))) short bf16x8;
typedef __attribute__((ext_vector_type(4))) float f32x4;

#define DEVI __device__ __forceinline__

// exp2 everywhere: Q pre-scaled by (1/sqrt(32))*log2(e) in the qkv-GEMM epilogue.
#define QSCALE 0.2550348744f        /* (1/sqrt(32)) * log2(e) */
#if __has_builtin(__builtin_amdgcn_exp2f)
DEVI float exp2x(float x) { return __builtin_amdgcn_exp2f(x); }
#else
DEVI float exp2x(float x) { float r; asm("v_exp_f32 %0, %1" : "=v"(r) : "v"(x)); return r; }
#endif

DEVI unsigned short f2bf(float f) {
  __hip_bfloat16 h = __float2bfloat16(f);
  return *reinterpret_cast<unsigned short*>(&h);
}

DEVI float bf2f(unsigned short u) {
  union { unsigned u; float f; } v; v.u = ((unsigned)u) << 16; return v.f;
}

DEVI unsigned cvtpk(float lo, float hi) {
  unsigned r;
  asm("v_cvt_pk_bf16_f32 %0, %1, %2" : "=v"(r) : "v"(lo), "v"(hi));
  return r;
}

DEVI void gload16(const void* g, void* l) {
  __builtin_amdgcn_global_load_lds((const __attribute__((address_space(1))) void*)g,
                                   (__attribute__((address_space(3))) void*)l, 16, 0, 0);
}

// ---------------- fused: LN1+transpose (blocks 0..511) | weight casts (blocks 512..1279) ----------------
__global__ __launch_bounds__(256) void k_pre(const float* __restrict__ x,
                                             const float* __restrict__ g,
                                             const float* __restrict__ be,
                                             unsigned short* __restrict__ xt,
                                             unsigned short* __restrict__ xln,
                                             const float* __restrict__ wa, const float* __restrict__ wb,
                                             const float* __restrict__ wc, const float* __restrict__ wd,
                                             unsigned short* __restrict__ oa, unsigned short* __restrict__ ob,
                                             unsigned short* __restrict__ oc, unsigned short* __restrict__ od) {
  __shared__ float tile[256][33];
  const int t = threadIdx.x;
  if (blockIdx.x >= 512) {
    const int i4 = ((blockIdx.x - 512) * 256 + t) * 4;
    const float* src; unsigned short* dst; int off;
    if (i4 < 196608)      { src = wa; dst = oa; off = 0; }
    else if (i4 < 262144) { src = wb; dst = ob; off = 196608; }
    else if (i4 < 524288) { src = wc; dst = oc; off = 262144; }
    else                  { src = wd; dst = od; off = 524288; }
    const int j = i4 - off;
    const float4 v = *(const float4*)(src + j);
    ushort4 o;
    o.x = f2bf(v.x); o.y = f2bf(v.y); o.z = f2bf(v.z); o.w = f2bf(v.w);
    *(ushort4*)(dst + j) = o;
    return;
  }
  const int b  = blockIdx.x >> 5;
  const int p0 = (blockIdx.x & 31) * 32;
  const float* src = x + ((size_t)b * 256 + t) * 1024 + p0;
#pragma unroll
  for (int j = 0; j < 32; j += 4) {
    float4 v = *(const float4*)(src + j);
    tile[t][j] = v.x; tile[t][j + 1] = v.y; tile[t][j + 2] = v.z; tile[t][j + 3] = v.w;
  }
  __syncthreads();
  const int w = t >> 6, l = t & 63;
#pragma unroll
  for (int i = 0; i < 8; i++) {
    const int p = w * 8 + i;
    float s = 0.f, ss = 0.f;
#pragma unroll
    for (int q = 0; q < 4; q++) {
      float v = tile[l + 64 * q][p];
      s += v; ss += v * v;
    }
#pragma unroll
    for (int msk = 1; msk < 64; msk <<= 1) {
      s  += __shfl_xor(s, msk);
      ss += __shfl_xor(ss, msk);
    }
    const float mean = s * (1.f / 256.f);
    const float var  = ss * (1.f / 256.f) - mean * mean;
    const float rs   = rsqrtf(var + 1e-5f);
    const size_t token = (size_t)b * 1024 + p0 + p;
#pragma unroll
    for (int q = 0; q < 4; q++) {
      const int c = l + 64 * q;
      const float v = tile[c][p];
      xt[token * 256 + c]  = f2bf(v);
      xln[token * 256 + c] = f2bf((v - mean) * rs * g[c] + be[c]);
    }
  }
}

// ---------------- GEMM: C[M,N] = A[M,K] @ B[N,K]^T, bf16 in, fp32 acc ----------------
// Double-buffered LDS, 1 barrier per k-step. T2 XOR-swizzled LDS tiles.
// EPI 0: store bf16 (qkv); Q cols pre-scaled by QSCALE; n0>=512 (V): swapped MFMA -> vT
// EPI 3: swapped MFMA; +bias +bf16 addend -> out[b][c][s] fp32 (folds transpose)
template <int EPI, int NN, int BM>
__global__ __launch_bounds__(256) void k_gemm(const unsigned short* __restrict__ A, int lda,
                                              const unsigned short* __restrict__ Bw, int ldb,
                                              int K,
                                              const float* __restrict__ bias,
                                              const unsigned short* __restrict__ addend, int ldadd,
                                              float* __restrict__ outf,
                                              unsigned short* __restrict__ outb, int ldc,
                                              unsigned short* __restrict__ vtb) {
  constexpr int MI = BM / 32;
  constexpr int IA = (BM * 64) / 2048;
  __shared__ __align__(16) unsigned short As[2][BM * 64];
  __shared__ __align__(16) unsigned short Bs[2][128 * 64];
  const int nwg = gridDim.x;
  const int id  = (blockIdx.x & 7) * (nwg >> 3) + (blockIdx.x >> 3);
  const int m0  = (id / NN) * BM, n0 = (id % NN) * 128;
  const int t  = threadIdx.x;
  const int w  = t >> 6, l = t & 63;
  const int wm = (w >> 1) * (BM / 2), wn = (w & 1) * 64;
  const int lr = l & 15, hi = l >> 4;
  const bool swp = (EPI == 3) || ((EPI == 0) && (n0 >= 512));
  const float qs = ((EPI == 0) && (n0 < 256)) ? QSCALE : 1.f;
  f32x4 acc[MI][4] = {};
  const int nkt = K >> 6;
  const int e   = t * 8;
  const int er  = e >> 6;
  const int ecs = (((t & 7) ^ (er & 7)) * 8);   // pre-swizzled source column
  const int sxr = lr & 7;

#pragma unroll
  for (int i = 0; i < IA; i++)
    gload16(&A[(size_t)(m0 + er + i * 32) * lda + ecs], &As[0][e + i * 2048]);
#pragma unroll
  for (int i = 0; i < 4; i++)
    gload16(&Bw[(size_t)(n0 + er + i * 32) * ldb + ecs], &Bs[0][e + i * 2048]);

  for (int kt = 0; kt < nkt; ++kt) {
    const int cur = kt & 1;
    __syncthreads();
    if (kt + 1 < nkt) {
      const int kn = (kt + 1) * 64;
#pragma unroll
      for (int i = 0; i < IA; i++)
        gload16(&A[(size_t)(m0 + er + i * 32) * lda + kn + ecs], &As[cur ^ 1][e + i * 2048]);
#pragma unroll
      for (int i = 0; i < 4; i++)
        gload16(&Bw[(size_t)(n0 + er + i * 32) * ldb + kn + ecs], &Bs[cur ^ 1][e + i * 2048]);
    }
#pragma unroll
    for (int ks = 0; ks < 2; ks++) {
      const int sA = ((ks * 4 + hi) ^ sxr) * 8;
      bf16x8 af[MI], bfr[4];
#pragma unroll
      for (int i = 0; i < MI; i++) af[i] = *(const bf16x8*)&As[cur][(wm + i * 16 + lr) * 64 + sA];
#pragma unroll
      for (int j = 0; j < 4; j++) bfr[j] = *(const bf16x8*)&Bs[cur][(wn + j * 16 + lr) * 64 + sA];
      if (swp) {
#pragma unroll
        for (int i = 0; i < MI; i++)
#pragma unroll
          for (int j = 0; j < 4; j++)
            acc[i][j] = __builtin_amdgcn_mfma_f32_16x16x32_bf16(bfr[j], af[i], acc[i][j], 0, 0, 0);
      } else {
#pragma unroll
        for (int i = 0; i < MI; i++)
#pragma unroll
          for (int j = 0; j < 4; j++)
            acc[i][j] = __builtin_amdgcn_mfma_f32_16x16x32_bf16(af[i], bfr[j], acc[i][j], 0, 0, 0);
      }
    }
  }

  if constexpr (EPI == 3) {
#pragma unroll
    for (int i = 0; i < MI; i++)
#pragma unroll
      for (int j = 0; j < 4; j++)
#pragma unroll
        for (int r = 0; r < 4; r++) {
          const int c  = n0 + wn + j * 16 + hi * 4 + r;
          const int gm = m0 + wm + i * 16 + lr;
          const int b  = gm >> 10, sI = gm & 1023;
          outf[((size_t)b * 256 + c) * 1024 + sI] =
              acc[i][j][r] + bias[c] + bf2f(addend[(size_t)gm * 256 + c]);
        }
    return;
  }
  if ((EPI == 0) && (n0 >= 512)) {
#pragma unroll
    for (int i = 0; i < MI; i++)
#pragma unroll
      for (int j = 0; j < 4; j++)
#pragma unroll
        for (int r = 0; r < 4; r++) {
          const int gn = n0 + wn + j * 16 + hi * 4 + r;
          const int gm = m0 + wm + i * 16 + lr;
          const int c = gn - 512;
          const int b = gm >> 10;
          vtb[(size_t)(b * 256 + c) * 1024 + (gm & 1023)] = f2bf(acc[i][j][r]);
        }
    return;
  }
#pragma unroll
  for (int i = 0; i < MI; i++)
#pragma unroll
    for (int j = 0; j < 4; j++)
#pragma unroll
      for (int r = 0; r < 4; r++) {
        const int gr = m0 + wm + i * 16 + hi * 4 + r;
        const int gc = n0 + wn + j * 16 + lr;
        const float v = acc[i][j][r];
        if constexpr (EPI == 0) {
          outb[(size_t)gr * ldc + gc] = f2bf(v * qs);
        }
      }
}

// ---------------- 8-wave GEMM (512 thr): BM=128 x BN=128, relu epilogue (ffn1) ----------------
__global__ __launch_bounds__(512) void k_gemm8w(const unsigned short* __restrict__ A,
                                                const unsigned short* __restrict__ Bw,
                                                const float* __restrict__ bias,
                                                unsigned short* __restrict__ outb) {
  __shared__ __align__(16) unsigned short As[2][128 * 64];
  __shared__ __align__(16) unsigned short Bs[2][128 * 64];
  const int nwg = gridDim.x;
  const int id  = (blockIdx.x & 7) * (nwg >> 3) + (blockIdx.x >> 3);
  const int m0  = (id >> 3) * 128, n0 = (id & 7) * 128;
  const int t  = threadIdx.x;
  const int w  = t >> 6, l = t & 63;
  const int wm = (w >> 1) * 32, wn = (w & 1) * 64;
  const int lr = l & 15, hi = l >> 4;
  f32x4 acc[2][4] = {};
  const int e   = t * 8;
  const int er  = e >> 6;
  const int ecs = (((t & 7) ^ (er & 7)) * 8);
  const int sxr = lr & 7;

#pragma unroll
  for (int i = 0; i < 2; i++) {
    gload16(&A[(size_t)(m0 + er + i * 64) * 256 + ecs], &As[0][e + i * 4096]);
    gload16(&Bw[(size_t)(n0 + er + i * 64) * 256 + ecs], &Bs[0][e + i * 4096]);
  }

  for (int kt = 0; kt < 4; ++kt) {
    const int cur = kt & 1;
    __syncthreads();
    if (kt < 3) {
      const int kn = (kt + 1) * 64;
#pragma unroll
      for (int i = 0; i < 2; i++) {
        gload16(&A[(size_t)(m0 + er + i * 64) * 256 + kn + ecs], &As[cur ^ 1][e + i * 4096]);
        gload16(&Bw[(size_t)(n0 + er + i * 64) * 256 + kn + ecs], &Bs[cur ^ 1][e + i * 4096]);
      }
    }
#pragma unroll
    for (int ks = 0; ks < 2; ks++) {
      const int sA = ((ks * 4 + hi) ^ sxr) * 8;
      bf16x8 af[2], bfr[4];
#pragma unroll
      for (int i = 0; i < 2; i++) af[i] = *(const bf16x8*)&As[cur][(wm + i * 16 + lr) * 64 + sA];
#pragma unroll
      for (int j = 0; j < 4; j++) bfr[j] = *(const bf16x8*)&Bs[cur][(wn + j * 16 + lr) * 64 + sA];
#pragma unroll
      for (int i = 0; i < 2; i++)
#pragma unroll
        for (int j = 0; j < 4; j++)
          acc[i][j] = __builtin_amdgcn_mfma_f32_16x16x32_bf16(af[i], bfr[j], acc[i][j], 0, 0, 0);
    }
  }

#pragma unroll
  for (int i = 0; i < 2; i++)
#pragma unroll
    for (int j = 0; j < 4; j++)
#pragma unroll
      for (int r = 0; r < 4; r++) {
        const int gr = m0 + wm + i * 16 + hi * 4 + r;
        const int gc = n0 + wn + j * 16 + lr;
        const float z = acc[i][j][r] + bias[gc];
        outb[(size_t)gr * 1024 + gc] = f2bf(z > 0.f ? z : 0.f);
      }
}

// ---------------- proj-GEMM + residual + LN2 fused (BM=32, BN=256), T2-swizzled ----------------
__global__ __launch_bounds__(256) void k_gemm1ln(const unsigned short* __restrict__ A,
                                                 const unsigned short* __restrict__ Bw,
                                                 const float* __restrict__ bias,
                                                 const unsigned short* __restrict__ xt,
                                                 const float* __restrict__ g2,
                                                 const float* __restrict__ be2,
                                                 unsigned short* __restrict__ y,
                                                 unsigned short* __restrict__ yln) {
  __shared__ __align__(16) unsigned short As[2][32 * 64];
  __shared__ __align__(16) unsigned short Bs[2][256 * 64];
  __shared__ float red[32][4][2];
  __shared__ float2 stats[32];
  const int id = (blockIdx.x & 7) * 64 + (blockIdx.x >> 3);  // bijective (512 % 8 == 0)
  const int m0 = id * 32;
  const int t  = threadIdx.x;
  const int w  = t >> 6, l = t & 63;
  const int wn = w * 64;
  const int lr = l & 15, hi = l >> 4;
  f32x4 acc[2][4] = {};
  const int e   = t * 8;
  const int er  = e >> 6;
  const int ecs = (((t & 7) ^ (er & 7)) * 8);
  const int sxr = lr & 7;

  gload16(&A[(size_t)(m0 + er) * 256 + ecs], &As[0][e]);
#pragma unroll
  for (int i = 0; i < 8; i++)
    gload16(&Bw[(size_t)(er + i * 32) * 256 + ecs], &Bs[0][e + i * 2048]);

  for (int kt = 0; kt < 4; ++kt) {
    const int cur = kt & 1;
    __syncthreads();
    if (kt < 3) {
      const int kn = (kt + 1) * 64;
      gload16(&A[(size_t)(m0 + er) * 256 + kn + ecs], &As[cur ^ 1][e]);
#pragma unroll
      for (int i = 0; i < 8; i++)
        gload16(&Bw[(size_t)(er + i * 32) * 256 + kn + ecs], &Bs[cur ^ 1][e + i * 2048]);
    }
#pragma unroll
    for (int ks = 0; ks < 2; ks++) {
      const int sA = ((ks * 4 + hi) ^ sxr) * 8;
      bf16x8 af[2], bfr[4];
#pragma unroll
      for (int i = 0; i < 2; i++) af[i] = *(const bf16x8*)&As[cur][(i * 16 + lr) * 64 + sA];
#pragma unroll
      for (int j = 0; j < 4; j++) bfr[j] = *(const bf16x8*)&Bs[cur][(wn + j * 16 + lr) * 64 + sA];
#pragma unroll
      for (int i = 0; i < 2; i++)
#pragma unroll
        for (int j = 0; j < 4; j++)
          acc[i][j] = __builtin_amdgcn_mfma_f32_16x16x32_bf16(af[i], bfr[j], acc[i][j], 0, 0, 0);
    }
  }

#pragma unroll
  for (int i = 0; i < 2; i++)
#pragma unroll
    for (int j = 0; j < 4; j++)
#pragma unroll
      for (int r = 0; r < 4; r++) {
        const int gr = i * 16 + hi * 4 + r;
        const int gc = wn + j * 16 + lr;
        acc[i][j][r] += bias[gc] + bf2f(xt[(size_t)(m0 + gr) * 256 + gc]);
      }

#pragma unroll
  for (int i = 0; i < 2; i++)
#pragma unroll
    for (int r = 0; r < 4; r++) {
      float s = 0.f, ss = 0.f;
#pragma unroll
      for (int j = 0; j < 4; j++) {
        const float v = acc[i][j][r];
        s += v; ss += v * v;
      }
#pragma unroll
      for (int msk = 1; msk < 16; msk <<= 1) {
        s  += __shfl_xor(s, msk);
        ss += __shfl_xor(ss, msk);
      }
      if (lr == 0) {
        red[i * 16 + hi * 4 + r][w][0] = s;
        red[i * 16 + hi * 4 + r][w][1] = ss;
      }
    }
  __syncthreads();
  if (t < 32) {
    const float s  = red[t][0][0] + red[t][1][0] + red[t][2][0] + red[t][3][0];
    const float ss = red[t][0][1] + red[t][1][1] + red[t][2][1] + red[t][3][1];
    const float mean = s * (1.f / 256.f);
    const float var  = ss * (1.f / 256.f) - mean * mean;
    stats[t] = make_float2(mean, rsqrtf(var + 1e-5f));
  }
  __syncthreads();

#pragma unroll
  for (int i = 0; i < 2; i++)
#pragma unroll
    for (int r = 0; r < 4; r++) {
      const int gr = i * 16 + hi * 4 + r;
      const float2 st = stats[gr];
      const size_t rowoff = (size_t)(m0 + gr) * 256;
#pragma unroll
      for (int j = 0; j < 4; j++) {
        const int gc = wn + j * 16 + lr;
        const float v = acc[i][j][r];
        y[rowoff + gc]   = f2bf(v);
        yln[rowoff + gc] = f2bf((v - st.x) * st.y * g2[gc] + be2[gc]);
      }
    }
}

// ---------------- flash attention: 512 thr / 8 waves, qi=4 (512 q-rows/block), dbuf LDS ----------------
__global__ __launch_bounds__(512, 1) void k_attn(const unsigned short* __restrict__ qkv,
                                                 const unsigned short* __restrict__ vt,
                                                 unsigned short* __restrict__ attn_out) {
  __shared__ __align__(16) unsigned short Ks[2][2][64][40];
  __shared__ __align__(16) unsigned short Vs[2][2][32][72];

  const int bid  = blockIdx.x;
  const int wgid = (bid & 7) * 32 + (bid >> 3);  // bijective (256 % 8 == 0)
  const int bh = wgid >> 1;
  const int qt = wgid & 1;
  const int b = bh >> 3, h = bh & 7;
  const int q0 = qt * 512;
  const int t = threadIdx.x, w = t >> 6, l = t & 63;
  const int lr = l & 15, hi = l >> 4, lk = hi * 8;
  const size_t base  = (size_t)b * 1024 * 512;
  const size_t vbase = (size_t)bh * 32 * 1024;

  bf16x8 qf[4];
#pragma unroll
  for (int qi = 0; qi < 4; qi++)
    qf[qi] = *(const bf16x8*)&qkv[base + (size_t)(q0 + w * 64 + qi * 16 + lr) * 512 + h * 32 + lk];

  f32x4 o0[4] = {}, o1[4] = {}, o_s[4] = {};
  const f32x4 z4 = {0.f, 0.f, 0.f, 0.f};
  const bf16x8 ones = {16256, 16256, 16256, 16256, 16256, 16256, 16256, 16256};  // bf16 1.0

  const int stok = t >> 2;             // 0..127
  const int sd0  = (t & 3) * 8;
  const int ksub = stok >> 6;
  const int krow = stok & 63;
  const int prow = ((krow >> 2) & 1) * 16 + ((krow >> 3) & 3) * 4 + (krow & 3) + (krow & 32);
  const int vsd  = t >> 4;             // 0..31
  const int vtk  = (t & 15) * 8;       // 0..120
  const int vsub = vtk >> 6;
  const int voff = vtk & 63;

  const unsigned short* pk = &qkv[base + (size_t)stok * 512 + 256 + h * 32 + sd0];
  const unsigned short* pv = &vt[vbase + (size_t)vsd * 1024 + vtk];
  bf16x8 nk = *(const bf16x8*)pk;
  bf16x8 nv = *(const bf16x8*)pv;

  for (int it = 0; it < 8; ++it) {
    const int cur = it & 1;
    *(bf16x8*)&Ks[cur][ksub][prow][sd0] = nk;
    *(bf16x8*)&Vs[cur][vsub][vsd][voff] = nv;
    __syncthreads();

    if (it < 7) {
      pk += 128 * 512;
      pv += 128;
      nk = *(const bf16x8*)pk;
      nv = *(const bf16x8*)pv;
    }

#pragma unroll
    for (int sub = 0; sub < 2; ++sub) {
      bf16x8 kf[4];
#pragma unroll
      for (int blk = 0; blk < 4; blk++)
        kf[blk] = *(const bf16x8*)&Ks[cur][sub][blk * 16 + lr][lk];

      union U { unsigned u[4]; bf16x8 v; };
      U pa[4][2];
#pragma unroll
      for (int qi = 0; qi < 4; qi++) {
        f32x4 s[4];
        __builtin_amdgcn_s_setprio(1);
#pragma unroll
        for (int blk = 0; blk < 4; blk++)
          s[blk] = __builtin_amdgcn_mfma_f32_16x16x32_bf16(kf[blk], qf[qi], z4, 0, 0, 0);
        __builtin_amdgcn_s_setprio(0);
#pragma unroll
        for (int blk = 0; blk < 4; blk++) {
          const float p0 = exp2x(s[blk][0]);
          const float p1 = exp2x(s[blk][1]);
          const float p2 = exp2x(s[blk][2]);
          const float p3 = exp2x(s[blk][3]);
          pa[qi][blk >> 1].u[(blk & 1) * 2]     = cvtpk(p0, p1);
          pa[qi][blk >> 1].u[(blk & 1) * 2 + 1] = cvtpk(p2, p3);
        }
      }

      __builtin_amdgcn_s_setprio(1);
#pragma unroll
      for (int ks = 0; ks < 2; ks++) {
        const bf16x8 v0f = *(const bf16x8*)&Vs[cur][sub][lr][ks * 32 + lk];
        const bf16x8 v1f = *(const bf16x8*)&Vs[cur][sub][16 + lr][ks * 32 + lk];
#pragma unroll
        for (int qi = 0; qi < 4; qi++) {
          o0[qi]  = __builtin_amdgcn_mfma_f32_16x16x32_bf16(pa[qi][ks].v, v0f, o0[qi], 0, 0, 0);
          o1[qi]  = __builtin_amdgcn_mfma_f32_16x16x32_bf16(pa[qi][ks].v, v1f, o1[qi], 0, 0, 0);
          o_s[qi] = __builtin_amdgcn_mfma_f32_16x16x32_bf16(pa[qi][ks].v, ones, o_s[qi], 0, 0, 0);
        }
      }
      __builtin_amdgcn_s_setprio(0);
    }
  }

#pragma unroll
  for (int qi = 0; qi < 4; qi++)
#pragma unroll
    for (int r = 0; r < 4; r++) {
      const float inv = __builtin_amdgcn_rcpf(o_s[qi][r]);
      const int row = q0 + w * 64 + qi * 16 + hi * 4 + r;
      attn_out[(size_t)(b * 1024 + row) * 256 + h * 32 + lr]      = f2bf(o0[qi][r] * inv);
      attn_out[(size_t)(b * 1024 + row) * 256 + h * 32 + 16 + lr] = f2bf(o1[qi][r] * inv);
    }
}

// ---------------- launch ----------------
extern "C" void kernel_launch(void* const* d_in, const int* in_sizes, int n_in,
                              void* d_out, int out_size, void* d_ws, size_t ws_size,
                              hipStream_t stream) {
  const float* x      = (const float*)d_in[0];
  const float* w_qkv  = (const float*)d_in[1];
  const float* w_proj = (const float*)d_in[2];
  const float* b_proj = (const float*)d_in[3];
  const float* g1     = (const float*)d_in[4];
  const float* beta1  = (const float*)d_in[5];
  const float* g2     = (const float*)d_in[6];
  const float* beta2  = (const float*)d_in[7];
  const float* w1     = (const float*)d_in[8];
  const float* b1     = (const float*)d_in[9];
  const float* w2     = (const float*)d_in[10];
  const float* b2     = (const float*)d_in[11];
  float* out = (float*)d_out;
  char* ws = (char*)d_ws;

  constexpr size_t OFF_XT  = 0;                       //  8 MB bf16 [tok][256]
  constexpr size_t OFF_XLN = 16777216;                //  8 MB bf16
  constexpr size_t OFF_QKV = OFF_XLN + 8388608;       // 16 MB bf16 [tok][512] (Q,K only)
  constexpr size_t OFF_ATT = OFF_QKV + 16777216;      //  8 MB bf16
  constexpr size_t OFF_Y   = OFF_ATT + 8388608;       //  8 MB bf16 (aliases vT before gemm1ln)
  constexpr size_t OFF_YLN = OFF_Y + 16777216;        //  8 MB bf16
  constexpr size_t OFF_W   = OFF_YLN + 8388608;       // weights bf16
  constexpr size_t OFF_H1  = OFF_XLN;                 // alias: 32 MB bf16 [tok][1024]
  constexpr size_t OFF_VT  = OFF_Y;                   // alias: 8 MB bf16 [bh][32][1024]

  unsigned short* xt    = (unsigned short*)(ws + OFF_XT);
  unsigned short* xln   = (unsigned short*)(ws + OFF_XLN);
  unsigned short* qkv   = (unsigned short*)(ws + OFF_QKV);
  unsigned short* attn  = (unsigned short*)(ws + OFF_ATT);
  unsigned short* y     = (unsigned short*)(ws + OFF_Y);
  unsigned short* yln   = (unsigned short*)(ws + OFF_YLN);
  unsigned short* h1    = (unsigned short*)(ws + OFF_H1);
  unsigned short* vtb   = (unsigned short*)(ws + OFF_VT);
  unsigned short* wqkvb = (unsigned short*)(ws + OFF_W);
  unsigned short* wprjb = (unsigned short*)(ws + OFF_W + 393216);
  unsigned short* w1b   = (unsigned short*)(ws + OFF_W + 393216 + 131072);
  unsigned short* w2b   = (unsigned short*)(ws + OFF_W + 393216 + 131072 + 524288);

  // LN1+transpose (512 blocks) || weight casts (768 blocks)
  k_pre<<<1280, 256, 0, stream>>>(x, g1, beta1, xt, xln,
                                  w_qkv, w_proj, w1, w2, wqkvb, wprjb, w1b, w2b);

  // qkv = xln @ w_qkv^T : Q (log2-prescaled),K -> qkv[tok][512]; V -> vT[bh][d][tok]
  k_gemm<0, 6, 64><<<1536, 256, 0, stream>>>(xln, 256, wqkvb, 256, 256,
                                             nullptr, nullptr, 0, nullptr, qkv, 512, vtb);

  k_attn<<<256, 512, 0, stream>>>(qkv, vtb, attn);

  // y = attn @ w_proj^T + b_proj + xt ; yln = LN2(y)  (fused)
  k_gemm1ln<<<512, 256, 0, stream>>>(attn, wprjb, b_proj, xt, g2, beta2, y, yln);

  // h1 = relu(yln @ w1^T + b1)  (8-wave 128x128 tiles)
  k_gemm8w<<<1024, 512, 0, stream>>>(yln, w1b, b1, h1);

  // out = transpose(h1 @ w2^T + b2 + y)  (direct [b][c][s] write)
  k_gemm<3, 2, 64><<<512, 256, 0, stream>>>(h1, 1024, w2b, 1024, 1024,
                                            b2, y, 256, out, nullptr, 256, nullptr);
}